// Round 3
// baseline (1589.069 us; speedup 1.0000x reference)
//
#include <hip/hip_runtime.h>
#include <math.h>

// ---------------- problem constants ----------------
constexpr int BB = 32, PP = 49, EE = 256, VV = 32000, TT = 48, ST = 47;
#define AP 260   // As row stride (256 + 4 pad)
#define BP 68    // Bs row stride (64 + 4 pad)

// ---------------- ws layout (float offsets) ----------------
constexpr long long OFF_HBUF = 0;          // 2 * 32*256 ping-pong h
constexpr long long OFF_M0   = 16384;      // 32*256
constexpr long long OFF_GS   = 24576;      // 32*1024 g_static (+bih+bhh)
constexpr long long OFF_GPRE = 57344;      // 47*1024*32  [t][j4][b]
constexpr long long OFF_V    = 1597440;    // 32*49*256   [(b,p)][j]
constexpr long long OFF_HALL = 1998848;    // 1504*256    [(b,t)][j]
constexpr long long OFF_FO   = 2383872;    // 1504*512
constexpr long long OFF_HS   = 3153920;    // 1504*512  (_hh | _s)
constexpr long long OFF_CE   = 3923968;    // 1504*256  (c + hh)
constexpr long long OFF_PMAX = 4308992;    // 1504*500
constexpr long long OFF_PSUM = 5060992;    // 1504*500
constexpr long long OFF_PAI  = 5812992;    // 1504*500 (int)
constexpr long long OFF_ROWM = 6564992;    // 1504
constexpr long long OFF_ROWLS= 6566496;    // 1504
// B_hi recycled over GPRE..CE (dead after k_att): 8.192M bf16 = 4.096M floats
constexpr long long OFF_BHI  = 57344;      // ends 4251648 < OFF_PMAX  (bf16)
constexpr long long OFF_AHI  = 6568064;    // 1536*256 bf16 = 196608 floats
constexpr long long OFF_ALO  = 6764672;    // 196608 floats
constexpr long long OFF_BLO  = 6961280;    // 4.096M floats (bf16), ends 11155584
constexpr long long OFF_FLAGS= 11155584;   // 512 ints (32 b x 16 pad), zeroed per launch

// d_out layout: att [0,75200) ; logp [75200, 48203200) ; txt [48203200, 48204704)
constexpr long long OUT_LOGP = 75200;
constexpr long long OUT_TXT  = 48203200;

typedef __attribute__((ext_vector_type(8))) short bf8v;   // 8 bf16
typedef __attribute__((ext_vector_type(4))) float f4v;    // 4 fp32

__device__ __forceinline__ float sigf(float x) { return 1.0f / (1.0f + expf(-x)); }

__device__ __forceinline__ unsigned short f2bf(float x) {
  unsigned u = __float_as_uint(x);
  u += 0x7fffu + ((u >> 16) & 1u);   // round-to-nearest-even
  return (unsigned short)(u >> 16);
}

// ---------------- generic 47/49-row x 64-col fp32 GEMM tile, K=256 ----------------
template <int RPT, typename ALoad, typename Epi>
__device__ __forceinline__ void gemm_tile(
    float* As, float* Bs, int r_count,
    const float* __restrict__ Bglob, int ldb, int koff, int n0,
    ALoad aload, Epi epi)
{
  const int tid = threadIdx.x;
  const int cg = tid & 15, rg = tid >> 4;
  const int rbase = rg * RPT;

  for (int r = 0; r < r_count; ++r) As[r * AP + tid] = aload(r, tid);

  float acc[RPT][4];
#pragma unroll
  for (int j = 0; j < RPT; ++j)
#pragma unroll
    for (int c = 0; c < 4; ++c) acc[j][c] = 0.f;

  for (int kc0 = 0; kc0 < 256; kc0 += 32) {
    __syncthreads();
    {
      int c = tid >> 2, kq = (tid & 3) * 8;
      const float* src = Bglob + (long long)(n0 + c) * ldb + koff + kc0 + kq;
      float4 x0 = *(const float4*)src;
      float4 x1 = *(const float4*)(src + 4);
      Bs[(kq + 0) * BP + c] = x0.x; Bs[(kq + 1) * BP + c] = x0.y;
      Bs[(kq + 2) * BP + c] = x0.z; Bs[(kq + 3) * BP + c] = x0.w;
      Bs[(kq + 4) * BP + c] = x1.x; Bs[(kq + 5) * BP + c] = x1.y;
      Bs[(kq + 6) * BP + c] = x1.z; Bs[(kq + 7) * BP + c] = x1.w;
    }
    __syncthreads();
#pragma unroll
    for (int kc = 0; kc < 32; kc += 4) {
      float4 b0 = *(float4*)&Bs[(kc + 0) * BP + cg * 4];
      float4 b1 = *(float4*)&Bs[(kc + 1) * BP + cg * 4];
      float4 b2 = *(float4*)&Bs[(kc + 2) * BP + cg * 4];
      float4 b3 = *(float4*)&Bs[(kc + 3) * BP + cg * 4];
#pragma unroll
      for (int j = 0; j < RPT; ++j) {
        int r = rbase + j;
        if (r < r_count) {
          float4 a = *(float4*)&As[r * AP + kc0 + kc];
          acc[j][0] += a.x * b0.x + a.y * b1.x + a.z * b2.x + a.w * b3.x;
          acc[j][1] += a.x * b0.y + a.y * b1.y + a.z * b2.y + a.w * b3.y;
          acc[j][2] += a.x * b0.z + a.y * b1.z + a.z * b2.z + a.w * b3.z;
          acc[j][3] += a.x * b0.w + a.y * b1.w + a.z * b2.w + a.w * b3.w;
        }
      }
    }
  }
#pragma unroll
  for (int j = 0; j < RPT; ++j) {
    int r = rbase + j;
    if (r < r_count) {
      float4 o = make_float4(acc[j][0], acc[j][1], acc[j][2], acc[j][3]);
      epi(r, cg * 4, o);
    }
  }
}

// ---------------- k_prep: mean, h0, m0, g_static ----------------
__global__ __launch_bounds__(256) void k_prep(
    const float* __restrict__ image, const float* __restrict__ vp,
    const float* __restrict__ label, const float* __restrict__ topic,
    const float* __restrict__ Wh, const float* __restrict__ bh,
    const float* __restrict__ Wm, const float* __restrict__ bm,
    const float* __restrict__ Wih, const float* __restrict__ bih,
    const float* __restrict__ bhh, float* __restrict__ ws)
{
  __shared__ float xs[536];
  int b = blockIdx.x, tid = threadIdx.x;
  float s = 0.f;
  for (int p = 0; p < PP; ++p) s += image[(b * PP + p) * EE + tid];
  xs[tid] = s * (1.0f / 49.0f);
  if (tid < 8)  xs[256 + tid] = vp[b * 8 + tid];
  if (tid < 16) xs[264 + tid] = label[b * 16 + tid];
  xs[280 + tid] = topic[b * 256 + tid];
  __syncthreads();
  float ah = bh[tid], am = bm[tid];
  for (int k = 0; k < 256; ++k) {
    float mk = xs[k];
    ah += mk * Wh[tid * 256 + k];
    am += mk * Wm[tid * 256 + k];
  }
  ws[OFF_HBUF + b * 256 + tid] = tanhf(ah);
  ws[OFF_M0   + b * 256 + tid] = tanhf(am);
  float a0 = bih[tid]       + bhh[tid];
  float a1 = bih[256 + tid] + bhh[256 + tid];
  float a2 = bih[512 + tid] + bhh[512 + tid];
  float a3 = bih[768 + tid] + bhh[768 + tid];
  for (int k = 0; k < 536; ++k) {
    float xk = xs[k];
    a0 += xk * Wih[(0 * 256 + tid) * 792 + k];
    a1 += xk * Wih[(1 * 256 + tid) * 792 + k];
    a2 += xk * Wih[(2 * 256 + tid) * 792 + k];
    a3 += xk * Wih[(3 * 256 + tid) * 792 + k];
  }
  float* gs = ws + OFF_GS + b * 1024;
  gs[tid] = a0; gs[256 + tid] = a1; gs[512 + tid] = a2; gs[768 + tid] = a3;
}

// ---------------- k_v: v = image @ Wv.T + bv ----------------
__global__ __launch_bounds__(256) void k_v(const float* __restrict__ image,
    const float* __restrict__ Wv, const float* __restrict__ bv, float* __restrict__ ws)
{
  __shared__ float As[PP * AP]; __shared__ float Bs[32 * BP];
  int nt = blockIdx.x, b = blockIdx.y, n0 = nt * 64;
  float* v = ws + OFF_V;
  gemm_tile<4>(As, Bs, 49, Wv, 256, 0, n0,
    [&](int r, int k) { return image[(b * PP + r) * EE + k]; },
    [&](int r, int c0, float4 o) {
      float4 bb = *(const float4*)&bv[n0 + c0];
      o.x += bb.x; o.y += bb.y; o.z += bb.z; o.w += bb.w;
      *(float4*)&v[(b * PP + r) * EE + n0 + c0] = o;
    });
}

// ---------------- k_gpre ----------------
__global__ __launch_bounds__(256) void k_gpre(const float* __restrict__ emb,
    const int* __restrict__ text, const float* __restrict__ Wih, float* __restrict__ ws)
{
  __shared__ float As[PP * AP]; __shared__ float Bs[32 * BP];
  int nt = blockIdx.x, b = blockIdx.y, n0 = nt * 64;
  const float* gs = ws + OFF_GS + b * 1024;
  float* gpre = ws + OFF_GPRE;
  gemm_tile<3>(As, Bs, 47, Wih, 792, 536, n0,
    [&](int r, int k) { return emb[(long long)text[b * TT + r] * EE + k]; },
    [&](int r, int c0, float4 o) {
      float* dst = gpre + (long long)r * 32768 + (n0 + c0) * 32 + b;
      dst[0]  = o.x + gs[n0 + c0];
      dst[32] = o.y + gs[n0 + c0 + 1];
      dst[64] = o.z + gs[n0 + c0 + 2];
      dst[96] = o.w + gs[n0 + c0 + 3];
    });
}

// ---------------- k_recur: LSTM recurrence, 32 groups (b) x 8 slices (q) ----------
// block (b,q) owns j in [32q, 32q+32), all 4 gates. Whh slice in VGPRs.
// thread: j_l = tid>>3, cc = tid&7 -> 4 gates x cols [32cc, 32cc+32).
// sync: per-producer flag (block (b,cc) produces the h cols this thread reads).
__global__ __launch_bounds__(256, 1) void k_recur(const float* __restrict__ Whh,
    float* __restrict__ ws)
{
  int tid = threadIdx.x;
  int b = blockIdx.x & 31, q = blockIdx.x >> 5;   // group's 8 blocks land on same XCD (heuristic)
  int j_l = tid >> 3, cc = tid & 7;
  int qj = q * 32 + j_l;                          // global j this octet owns

  // load Whh slice into registers: wreg[gate][c4] = 4 cols of row (gate*256+qj)
  float4 wreg[4][8];
#pragma unroll
  for (int gt = 0; gt < 4; ++gt) {
    const float* wr = Whh + (long long)((gt << 8) + qj) * 256 + (cc << 5);
#pragma unroll
    for (int c4 = 0; c4 < 8; ++c4) wreg[gt][c4] = *(const float4*)(wr + (c4 << 2));
  }

  float m = ws[OFF_M0 + b * 256 + qj];            // valid in lane cc==0 (others unused)
  float* hbuf = ws + OFF_HBUF;
  const float* gpre = ws + OFF_GPRE;
  float* h_all = ws + OFF_HALL;
  int* flags = (int*)(ws + OFF_FLAGS);
  int myflag = b * 16 + q;
  int srcflag = b * 16 + cc;

  for (int t = 0; t < ST; ++t) {
    // gate bias (gpre) for this j — independent of flags, issue early
    float g0 = 0.f, g1 = 0.f, g2 = 0.f, g3 = 0.f;
    if (cc == 0) {
      const float* gp = gpre + (long long)t * 32768;
      g0 = gp[((0 << 8) + qj) * 32 + b];
      g1 = gp[((1 << 8) + qj) * 32 + b];
      g2 = gp[((2 << 8) + qj) * 32 + b];
      g3 = gp[((3 << 8) + qj) * 32 + b];
    }
    // wait for producer of our h col-slice (block (b,cc)), then load h
    if (t > 0) {
      while (__hip_atomic_load(&flags[srcflag], __ATOMIC_ACQUIRE,
                               __HIP_MEMORY_SCOPE_AGENT) < t) {
        __builtin_amdgcn_s_sleep(2);
      }
    }
    const float* hsrc = hbuf + (t & 1) * 8192 + b * 256 + (cc << 5);
    float4 h4[8];
#pragma unroll
    for (int c4 = 0; c4 < 8; ++c4) h4[c4] = *(const float4*)(hsrc + (c4 << 2));

    float ai = 0.f, af = 0.f, ag = 0.f, ao = 0.f;
#pragma unroll
    for (int c4 = 0; c4 < 8; ++c4) {
      float4 hv = h4[c4];
      ai += wreg[0][c4].x * hv.x + wreg[0][c4].y * hv.y + wreg[0][c4].z * hv.z + wreg[0][c4].w * hv.w;
      af += wreg[1][c4].x * hv.x + wreg[1][c4].y * hv.y + wreg[1][c4].z * hv.z + wreg[1][c4].w * hv.w;
      ag += wreg[2][c4].x * hv.x + wreg[2][c4].y * hv.y + wreg[2][c4].z * hv.z + wreg[2][c4].w * hv.w;
      ao += wreg[3][c4].x * hv.x + wreg[3][c4].y * hv.y + wreg[3][c4].z * hv.z + wreg[3][c4].w * hv.w;
    }
    // reduce over the 8-lane octet (cc)
#pragma unroll
    for (int msk = 1; msk < 8; msk <<= 1) {
      ai += __shfl_xor(ai, msk, 64);
      af += __shfl_xor(af, msk, 64);
      ag += __shfl_xor(ag, msk, 64);
      ao += __shfl_xor(ao, msk, 64);
    }
    if (cc == 0) {
      ai += g0; af += g1; ag += g2; ao += g3;
      m = sigf(af) * m + sigf(ai) * tanhf(ag);
      float h = sigf(ao) * tanhf(m);
      hbuf[((t + 1) & 1) * 8192 + b * 256 + qj] = h;
      h_all[(long long)(b * ST + t) * 256 + qj] = h;
    }
    __syncthreads();                               // drains vmcnt before barrier
    if (t < ST - 1 && tid == 0) {
      __hip_atomic_store(&flags[myflag], t + 1, __ATOMIC_RELEASE,
                         __HIP_MEMORY_SCOPE_AGENT);
    }
  }
}

// ---------------- k_fc ----------------
__global__ __launch_bounds__(256) void k_fc(const float* __restrict__ Wfc,
    const float* __restrict__ bfc, float* __restrict__ ws)
{
  __shared__ float As[PP * AP]; __shared__ float Bs[32 * BP];
  int nt = blockIdx.x, b = blockIdx.y, n0 = nt * 64;
  const float* h_all = ws + OFF_HALL;
  float* FO = ws + OFF_FO;
  gemm_tile<3>(As, Bs, 47, Wfc, 256, 0, n0,
    [&](int r, int k) { return h_all[(long long)(b * ST + r) * 256 + k]; },
    [&](int r, int c0, float4 o) {
      float4 bb = *(const float4*)&bfc[n0 + c0];
      o.x = fmaxf(o.x + bb.x, 0.f); o.y = fmaxf(o.y + bb.y, 0.f);
      o.z = fmaxf(o.z + bb.z, 0.f); o.w = fmaxf(o.w + bb.w, 0.f);
      *(float4*)&FO[(long long)(b * ST + r) * 512 + n0 + c0] = o;
    });
}

// ---------------- k_hs ----------------
__global__ __launch_bounds__(256) void k_hs(const float* __restrict__ Whh2,
    const float* __restrict__ bhh2, const float* __restrict__ Wsw,
    const float* __restrict__ bsw, float* __restrict__ ws)
{
  __shared__ float As[PP * AP]; __shared__ float Bs[32 * BP];
  int nt = blockIdx.x, b = blockIdx.y;
  bool second = nt >= 4;
  int n0b = (nt & 3) * 64;
  const float* Bmat = second ? Wsw : Whh2;
  const float* bias = second ? bsw : bhh2;
  int aoff = second ? 256 : 0;
  int oout = second ? 256 : 0;
  const float* FO = ws + OFF_FO;
  float* HS = ws + OFF_HS;
  gemm_tile<3>(As, Bs, 47, Bmat, 256, 0, n0b,
    [&](int r, int k) { return FO[(long long)(b * ST + r) * 512 + aoff + k]; },
    [&](int r, int c0, float4 o) {
      float4 bb = *(const float4*)&bias[n0b + c0];
      o.x += bb.x; o.y += bb.y; o.z += bb.z; o.w += bb.w;
      *(float4*)&HS[(long long)(b * ST + r) * 512 + oout + n0b + c0] = o;
    });
}

// ---------------- k_att ----------------
__global__ __launch_bounds__(256) void k_att(const float* __restrict__ image,
    const float* __restrict__ Wz, const float* __restrict__ bz,
    const int* __restrict__ length, float* __restrict__ ws, float* __restrict__ out)
{
  int t = blockIdx.x, b = blockIdx.y, tid = threadIdx.x;
  int i = b * ST + t;
  float* att = out;
  bool valid = t < (length[b] - 1);
  if (!valid) {
    if (tid < 50) att[(long long)i * 50 + tid] = 0.f;
    return;
  }
  __shared__ float hhL[256], sL[256], hbL[256], sbL[256];
  __shared__ float zzL[52], aL[52];
  const float* FO = ws + OFF_FO;
  const float* HS = ws + OFF_HS;
  const float* v  = ws + OFF_V;
  float* CE = ws + OFF_CE;
  hhL[tid] = FO[(long long)i * 512 + tid];
  sL[tid]  = FO[(long long)i * 512 + 256 + tid];
  hbL[tid] = HS[(long long)i * 512 + tid];
  sbL[tid] = HS[(long long)i * 512 + 256 + tid];
  __syncthreads();
  int w = tid >> 6, l = tid & 63;
  for (int p = w; p < 50; p += 4) {
    int j0 = l * 4;
    float x0, x1, x2, x3;
    if (p < 49) {
      float4 vv = *(const float4*)&v[(long long)(b * PP + p) * EE + j0];
      x0 = vv.x; x1 = vv.y; x2 = vv.z; x3 = vv.w;
    } else {
      x0 = sbL[j0]; x1 = sbL[j0 + 1]; x2 = sbL[j0 + 2]; x3 = sbL[j0 + 3];
    }
    float4 wz4 = *(const float4*)&Wz[j0];
    float part = tanhf(x0 + hbL[j0]) * wz4.x + tanhf(x1 + hbL[j0 + 1]) * wz4.y
               + tanhf(x2 + hbL[j0 + 2]) * wz4.z + tanhf(x3 + hbL[j0 + 3]) * wz4.w;
    for (int o = 32; o; o >>= 1) part += __shfl_down(part, o, 64);
    if (l == 0) zzL[p] = part + bz[0];
  }
  __syncthreads();
  if (tid < 64) {
    float zv = (tid < 50) ? zzL[tid] : -3.4e38f;
    float mx = zv;
    for (int o = 32; o; o >>= 1) mx = fmaxf(mx, __shfl_xor(mx, o, 64));
    float e = (tid < 50) ? expf(zv - mx) : 0.f;
    float ssum = e;
    for (int o = 32; o; o >>= 1) ssum += __shfl_xor(ssum, o, 64);
    if (tid < 50) {
      float a = e / ssum;
      aL[tid] = a;
      att[(long long)i * 50 + tid] = a;
    }
  }
  __syncthreads();
  float cj = 0.f;
  for (int p = 0; p < 49; ++p) cj += aL[p] * image[(long long)(b * PP + p) * EE + tid];
  cj += aL[49] * sL[tid];
  CE[(long long)i * 256 + tid] = cj + hhL[tid];
}

// ---------------- k_cvtA: CE -> A-frag-layout bf16 hi/lo ----------------
__global__ __launch_bounds__(256) void k_cvtA(float* __restrict__ ws)
{
  int gid = blockIdx.x * 256 + threadIdx.x;   // 0..49151 (96*8*64)
  int lane = gid & 63;
  int kc = (gid >> 6) & 7;
  int mt16 = gid >> 9;
  int m = (mt16 << 4) + (lane & 15);
  int k0 = (kc << 5) + ((lane >> 4) << 3);
  float xs[8];
  if (m < 1504) {
    const float* src = ws + OFF_CE + (long long)m * 256 + k0;
    float4 a = *(const float4*)src;
    float4 c = *(const float4*)(src + 4);
    xs[0] = a.x; xs[1] = a.y; xs[2] = a.z; xs[3] = a.w;
    xs[4] = c.x; xs[5] = c.y; xs[6] = c.z; xs[7] = c.w;
  } else {
#pragma unroll
    for (int j = 0; j < 8; ++j) xs[j] = 0.f;
  }
  bf8v vh, vl;
#pragma unroll
  for (int j = 0; j < 8; ++j) {
    unsigned short h = f2bf(xs[j]);
    vh[j] = (short)h;
    vl[j] = (short)f2bf(xs[j] - __uint_as_float((unsigned)h << 16));
  }
  ((bf8v*)(ws + OFF_AHI))[gid] = vh;
  ((bf8v*)(ws + OFF_ALO))[gid] = vl;
}

// ---------------- k_cvtB: Wp -> B-frag-layout bf16 hi/lo ----------------
__global__ __launch_bounds__(256) void k_cvtB(const float* __restrict__ Wp,
                                              float* __restrict__ ws)
{
  int gid = blockIdx.x * 256 + threadIdx.x;   // 0..1023999 (2000*8*64)
  int lane = gid & 63;
  int kc = (gid >> 6) & 7;
  int nt16 = gid >> 9;
  int n = (nt16 << 4) + (lane & 15);
  int k0 = (kc << 5) + ((lane >> 4) << 3);
  const float* src = Wp + (long long)n * 256 + k0;
  float4 a = *(const float4*)src;
  float4 c = *(const float4*)(src + 4);
  float xs[8] = {a.x, a.y, a.z, a.w, c.x, c.y, c.z, c.w};
  bf8v vh, vl;
#pragma unroll
  for (int j = 0; j < 8; ++j) {
    unsigned short h = f2bf(xs[j]);
    vh[j] = (short)h;
    vl[j] = (short)f2bf(xs[j] - __uint_as_float((unsigned)h << 16));
  }
  ((bf8v*)(ws + OFF_BHI))[gid] = vh;
  ((bf8v*)(ws + OFF_BLO))[gid] = vl;
}

// ---------------- k_Dm: split-bf16 MFMA logits GEMM + softmax/argmax partials ----
__global__ __launch_bounds__(256) void k_Dm(const float* __restrict__ bp,
    const float* __restrict__ temp, float* __restrict__ ws, float* __restrict__ out)
{
  int tid = threadIdx.x;
  int wv = tid >> 6, lane = tid & 63, ln = lane & 15, quad = lane >> 4;
  int m0 = blockIdx.x * 64;
  int nw0 = blockIdx.y * 256 + wv * 64;
  const bf8v* Ah = (const bf8v*)(ws + OFF_AHI);
  const bf8v* Al = (const bf8v*)(ws + OFF_ALO);
  const bf8v* Bh = (const bf8v*)(ws + OFF_BHI);
  const bf8v* Bl = (const bf8v*)(ws + OFF_BLO);
  int mt0 = blockIdx.x * 4;
  int nt0 = nw0 >> 4;

  f4v acc[4][4];
#pragma unroll
  for (int mi = 0; mi < 4; ++mi)
#pragma unroll
    for (int ni = 0; ni < 4; ++ni) acc[mi][ni] = (f4v){0.f, 0.f, 0.f, 0.f};

  for (int kc = 0; kc < 8; ++kc) {
    bf8v ah[4], al[4];
#pragma unroll
    for (int mi = 0; mi < 4; ++mi) {
      int idx = (((mt0 + mi) << 3) + kc) * 64 + lane;
      ah[mi] = Ah[idx];
      al[mi] = Al[idx];
    }
#pragma unroll
    for (int ni = 0; ni < 4; ++ni) {
      int idx = (((nt0 + ni) << 3) + kc) * 64 + lane;
      bf8v bh = Bh[idx];
      bf8v bl = Bl[idx];
#pragma unroll
      for (int mi = 0; mi < 4; ++mi) {
        acc[mi][ni] = __builtin_amdgcn_mfma_f32_16x16x32_bf16(ah[mi], bh, acc[mi][ni], 0, 0, 0);
        acc[mi][ni] = __builtin_amdgcn_mfma_f32_16x16x32_bf16(al[mi], bh, acc[mi][ni], 0, 0, 0);
        acc[mi][ni] = __builtin_amdgcn_mfma_f32_16x16x32_bf16(ah[mi], bl, acc[mi][ni], 0, 0, 0);
      }
    }
  }

  float bpv[4];
#pragma unroll
  for (int ni = 0; ni < 4; ++ni) bpv[ni] = bp[nw0 + ni * 16 + ln];
  float* logp = out + OUT_LOGP;
  float* pmax = ws + OFF_PMAX;
  float* psum = ws + OFF_PSUM;
  int* pai = (int*)(ws + OFF_PAI);
  int ntidx = blockIdx.y * 4 + wv;

#pragma unroll
  for (int mi = 0; mi < 4; ++mi) {
    int row_base = m0 + mi * 16 + quad * 4;
#pragma unroll
    for (int r = 0; r < 4; ++r) {
      int row = row_base + r;
      if (row < 1504) {
        float x0 = acc[mi][0][r] + bpv[0];
        float x1 = acc[mi][1][r] + bpv[1];
        float x2 = acc[mi][2][r] + bpv[2];
        float x3 = acc[mi][3][r] + bpv[3];
        long long ro = (long long)row * VV + nw0 + ln;
        logp[ro]      = x0;
        logp[ro + 16] = x1;
        logp[ro + 32] = x2;
        logp[ro + 48] = x3;
        float mx = fmaxf(fmaxf(x0, x1), fmaxf(x2, x3));
#pragma unroll
        for (int msk = 1; msk < 16; msk <<= 1) mx = fmaxf(mx, __shfl_xor(mx, msk, 64));
        float it = 1.0f / temp[row / 47];
        float s = expf((x0 - mx) * it) + expf((x1 - mx) * it)
                + expf((x2 - mx) * it) + expf((x3 - mx) * it);
        float bv = x0; int bc = nw0 + ln;
        if (x1 > bv) { bv = x1; bc = nw0 + 16 + ln; }
        if (x2 > bv) { bv = x2; bc = nw0 + 32 + ln; }
        if (x3 > bv) { bv = x3; bc = nw0 + 48 + ln; }
#pragma unroll
        for (int msk = 1; msk < 16; msk <<= 1) {
          s += __shfl_xor(s, msk, 64);
          float ov = __shfl_xor(bv, msk, 64);
          int oc = __shfl_xor(bc, msk, 64);
          if (ov > bv || (ov == bv && oc < bc)) { bv = ov; bc = oc; }
        }
        if (ln == 0) {
          long long ii = (long long)row * 500 + ntidx;
          pmax[ii] = mx;
          psum[ii] = s;
          pai[ii] = bc;
        }
      }
    }
  }
}

// ---------------- k_E0: reduce per-tile partials -> row stats + txt ----------------
__global__ __launch_bounds__(256) void k_E0(const int* __restrict__ length,
    const float* __restrict__ temp, float* __restrict__ ws, float* __restrict__ out)
{
  int i = blockIdx.x, tid = threadIdx.x;
  int b = i / ST, t = i % ST;
  float* txt = out + OUT_TXT;
  if (t >= length[b] - 1) { if (tid == 0) txt[i] = 0.f; return; }
  const float* pmax = ws + OFF_PMAX + (long long)i * 500;
  const float* psum = ws + OFF_PSUM + (long long)i * 500;
  const int* pai = (int*)(ws + OFF_PAI) + (long long)i * 500;
  __shared__ float sred[4]; __shared__ float s2[4]; __shared__ float s3[4]; __shared__ int s4[4];
  int w = tid >> 6;
  float mx = -3.4e38f;
  for (int nt = tid; nt < 500; nt += 256) mx = fmaxf(mx, pmax[nt]);
  for (int o = 32; o; o >>= 1) mx = fmaxf(mx, __shfl_xor(mx, o, 64));
  if ((tid & 63) == 0) sred[w] = mx;
  __syncthreads();
  float M = fmaxf(fmaxf(sred[0], sred[1]), fmaxf(sred[2], sred[3]));
  float it = 1.0f / temp[b];
  float S = 0.f; float bv = -3.4e38f; int bi = 0;
  for (int nt = tid; nt < 500; nt += 256) {
    float pm = pmax[nt];
    S += psum[nt] * expf((pm - M) * it);
    int ii = pai[nt];
    if (pm > bv || (pm == bv && ii < bi)) { bv = pm; bi = ii; }
  }
  for (int o = 32; o; o >>= 1) {
    S += __shfl_xor(S, o, 64);
    float vv = __shfl_xor(bv, o, 64);
    int ii = __shfl_xor(bi, o, 64);
    if (vv > bv || (vv == bv && ii < bi)) { bv = vv; bi = ii; }
  }
  if ((tid & 63) == 0) { s2[w] = S; s3[w] = bv; s4[w] = bi; }
  __syncthreads();
  if (tid == 0) {
    float St = s2[0] + s2[1] + s2[2] + s2[3];
    float bvv = s3[0]; int bii = s4[0];
    for (int u = 1; u < 4; ++u)
      if (s3[u] > bvv || (s3[u] == bvv && s4[u] < bii)) { bvv = s3[u]; bii = s4[u]; }
    ws[OFF_ROWM + i] = M;
    ws[OFF_ROWLS + i] = logf(St);
    txt[i] = (float)bii;
  }
}

// ---------------- k_E: in-place logits -> logp ----------------
__global__ __launch_bounds__(256) void k_E(const int* __restrict__ length,
    const float* __restrict__ temp, const float* __restrict__ ws, float* __restrict__ out)
{
  int i = blockIdx.y;
  int f4 = blockIdx.x * 256 + threadIdx.x;
  if (f4 >= 8000) return;
  int b = i / ST, t = i % ST;
  float4* p = (float4*)(out + OUT_LOGP + (long long)i * VV) + f4;
  if (t >= length[b] - 1) { *p = make_float4(0.f, 0.f, 0.f, 0.f); return; }
  float M = ws[OFF_ROWM + i], LS = ws[OFF_ROWLS + i];
  float it = 1.0f / temp[b];
  float4 x = *p;
  x.x = (x.x - M) * it - LS;
  x.y = (x.y - M) * it - LS;
  x.z = (x.z - M) * it - LS;
  x.w = (x.w - M) * it - LS;
  *p = x;
}

// ---------------- launch ----------------
extern "C" void kernel_launch(void* const* d_in, const int* in_sizes, int n_in,
                              void* d_out, int out_size, void* d_ws, size_t ws_size,
                              hipStream_t stream) {
  const float* image = (const float*)d_in[0];
  const float* vp    = (const float*)d_in[1];
  const float* label = (const float*)d_in[2];
  const float* topic = (const float*)d_in[3];
  const float* temp  = (const float*)d_in[4];
  const int*   text  = (const int*)d_in[5];
  const int*   length= (const int*)d_in[6];
  const float* emb   = (const float*)d_in[7];
  const float* Wv  = (const float*)d_in[8];  const float* bv  = (const float*)d_in[9];
  const float* Wh  = (const float*)d_in[10]; const float* bh  = (const float*)d_in[11];
  const float* Wm  = (const float*)d_in[12]; const float* bm  = (const float*)d_in[13];
  const float* Wih = (const float*)d_in[14]; const float* bih = (const float*)d_in[15];
  const float* Whh = (const float*)d_in[16]; const float* bhh = (const float*)d_in[17];
  const float* Wfc = (const float*)d_in[18]; const float* bfc = (const float*)d_in[19];
  const float* Whh2= (const float*)d_in[20]; const float* bhh2= (const float*)d_in[21];
  const float* Wsw = (const float*)d_in[22]; const float* bsw = (const float*)d_in[23];
  const float* Wz  = (const float*)d_in[24]; const float* bz  = (const float*)d_in[25];
  const float* Wp  = (const float*)d_in[26]; const float* bp  = (const float*)d_in[27];
  float* ws = (float*)d_ws;
  float* out = (float*)d_out;

  hipMemsetAsync(ws + OFF_FLAGS, 0, 512 * sizeof(int), stream);   // flags (poisoned 0xAA otherwise)
  k_prep<<<32, 256, 0, stream>>>(image, vp, label, topic, Wh, bh, Wm, bm, Wih, bih, bhh, ws);
  k_v<<<dim3(4, 32), 256, 0, stream>>>(image, Wv, bv, ws);
  k_gpre<<<dim3(16, 32), 256, 0, stream>>>(emb, text, Wih, ws);
  k_recur<<<256, 256, 0, stream>>>(Whh, ws);
  k_fc<<<dim3(8, 32), 256, 0, stream>>>(Wfc, bfc, ws);
  k_hs<<<dim3(8, 32), 256, 0, stream>>>(Whh2, bhh2, Wsw, bsw, ws);
  k_att<<<dim3(47, 32), 256, 0, stream>>>(image, Wz, bz, length, ws, out);
  k_cvtA<<<192, 256, 0, stream>>>(ws);
  k_cvtB<<<4000, 256, 0, stream>>>(Wp, ws);
  k_Dm<<<dim3(24, 125), 256, 0, stream>>>(bp, temp, ws, out);
  k_E0<<<1504, 256, 0, stream>>>(length, temp, ws, out);
  k_E<<<dim3(32, 1504), 256, 0, stream>>>(length, temp, ws, out);
}

// Round 4
// 1061.224 us; speedup vs baseline: 1.4974x; 1.4974x over previous
//
#include <hip/hip_runtime.h>
#include <math.h>

// ---------------- problem constants ----------------
constexpr int BB = 32, PP = 49, EE = 256, VV = 32000, TT = 48, ST = 47;
#define AP 260   // As row stride (256 + 4 pad)
#define BP 68    // Bs row stride (64 + 4 pad)

// ---------------- ws layout (float offsets) ----------------
constexpr long long OFF_HBUF = 0;          // 2 * 32*256 ping-pong h
constexpr long long OFF_M0   = 16384;      // 32*256
constexpr long long OFF_GS   = 24576;      // 32*1024 g_static (+bih+bhh)
constexpr long long OFF_GPRE = 57344;      // 47*1024*32  [t][j4][b]
constexpr long long OFF_V    = 1597440;    // 32*49*256   [(b,p)][j]
constexpr long long OFF_HALL = 1998848;    // 1504*256    [(b,t)][j]
constexpr long long OFF_FO   = 2383872;    // 1504*512
constexpr long long OFF_HS   = 3153920;    // 1504*512  (_hh | _s)
constexpr long long OFF_CE   = 3923968;    // 1504*256  (c + hh)
constexpr long long OFF_PMAX = 4308992;    // 1504*500
constexpr long long OFF_PSUM = 5060992;    // 1504*500
constexpr long long OFF_PAI  = 5812992;    // 1504*500 (int)
constexpr long long OFF_ROWM = 6564992;    // 1504
constexpr long long OFF_ROWLS= 6566496;    // 1504
// B_hi recycled over GPRE..CE (dead after k_att): 8.192M bf16 = 4.096M floats
constexpr long long OFF_BHI  = 57344;      // ends 4251648 < OFF_PMAX  (bf16)
constexpr long long OFF_AHI  = 6568064;    // 1536*256 bf16 = 196608 floats
constexpr long long OFF_ALO  = 6764672;    // 196608 floats
constexpr long long OFF_BLO  = 6961280;    // 4.096M floats (bf16), ends 11155584
constexpr long long OFF_FLAGS= 11155584;   // 512 ints (32 b x 16 pad), zeroed per launch

// d_out layout: att [0,75200) ; logp [75200, 48203200) ; txt [48203200, 48204704)
constexpr long long OUT_LOGP = 75200;
constexpr long long OUT_TXT  = 48203200;

typedef __attribute__((ext_vector_type(8))) short bf8v;   // 8 bf16
typedef __attribute__((ext_vector_type(4))) float f4v;    // 4 fp32

__device__ __forceinline__ float sigf(float x) { return 1.0f / (1.0f + expf(-x)); }

__device__ __forceinline__ unsigned short f2bf(float x) {
  unsigned u = __float_as_uint(x);
  u += 0x7fffu + ((u >> 16) & 1u);   // round-to-nearest-even
  return (unsigned short)(u >> 16);
}

// ---------------- generic 47/49-row x 64-col fp32 GEMM tile, K=256 ----------------
template <int RPT, typename ALoad, typename Epi>
__device__ __forceinline__ void gemm_tile(
    float* As, float* Bs, int r_count,
    const float* __restrict__ Bglob, int ldb, int koff, int n0,
    ALoad aload, Epi epi)
{
  const int tid = threadIdx.x;
  const int cg = tid & 15, rg = tid >> 4;
  const int rbase = rg * RPT;

  for (int r = 0; r < r_count; ++r) As[r * AP + tid] = aload(r, tid);

  float acc[RPT][4];
#pragma unroll
  for (int j = 0; j < RPT; ++j)
#pragma unroll
    for (int c = 0; c < 4; ++c) acc[j][c] = 0.f;

  for (int kc0 = 0; kc0 < 256; kc0 += 32) {
    __syncthreads();
    {
      int c = tid >> 2, kq = (tid & 3) * 8;
      const float* src = Bglob + (long long)(n0 + c) * ldb + koff + kc0 + kq;
      float4 x0 = *(const float4*)src;
      float4 x1 = *(const float4*)(src + 4);
      Bs[(kq + 0) * BP + c] = x0.x; Bs[(kq + 1) * BP + c] = x0.y;
      Bs[(kq + 2) * BP + c] = x0.z; Bs[(kq + 3) * BP + c] = x0.w;
      Bs[(kq + 4) * BP + c] = x1.x; Bs[(kq + 5) * BP + c] = x1.y;
      Bs[(kq + 6) * BP + c] = x1.z; Bs[(kq + 7) * BP + c] = x1.w;
    }
    __syncthreads();
#pragma unroll
    for (int kc = 0; kc < 32; kc += 4) {
      float4 b0 = *(float4*)&Bs[(kc + 0) * BP + cg * 4];
      float4 b1 = *(float4*)&Bs[(kc + 1) * BP + cg * 4];
      float4 b2 = *(float4*)&Bs[(kc + 2) * BP + cg * 4];
      float4 b3 = *(float4*)&Bs[(kc + 3) * BP + cg * 4];
#pragma unroll
      for (int j = 0; j < RPT; ++j) {
        int r = rbase + j;
        if (r < r_count) {
          float4 a = *(float4*)&As[r * AP + kc0 + kc];
          acc[j][0] += a.x * b0.x + a.y * b1.x + a.z * b2.x + a.w * b3.x;
          acc[j][1] += a.x * b0.y + a.y * b1.y + a.z * b2.y + a.w * b3.y;
          acc[j][2] += a.x * b0.z + a.y * b1.z + a.z * b2.z + a.w * b3.z;
          acc[j][3] += a.x * b0.w + a.y * b1.w + a.z * b2.w + a.w * b3.w;
        }
      }
    }
  }
#pragma unroll
  for (int j = 0; j < RPT; ++j) {
    int r = rbase + j;
    if (r < r_count) {
      float4 o = make_float4(acc[j][0], acc[j][1], acc[j][2], acc[j][3]);
      epi(r, cg * 4, o);
    }
  }
}

// ---------------- k_prep: mean, h0, m0, g_static ----------------
__global__ __launch_bounds__(256) void k_prep(
    const float* __restrict__ image, const float* __restrict__ vp,
    const float* __restrict__ label, const float* __restrict__ topic,
    const float* __restrict__ Wh, const float* __restrict__ bh,
    const float* __restrict__ Wm, const float* __restrict__ bm,
    const float* __restrict__ Wih, const float* __restrict__ bih,
    const float* __restrict__ bhh, float* __restrict__ ws)
{
  __shared__ float xs[536];
  int b = blockIdx.x, tid = threadIdx.x;
  float s = 0.f;
  for (int p = 0; p < PP; ++p) s += image[(b * PP + p) * EE + tid];
  xs[tid] = s * (1.0f / 49.0f);
  if (tid < 8)  xs[256 + tid] = vp[b * 8 + tid];
  if (tid < 16) xs[264 + tid] = label[b * 16 + tid];
  xs[280 + tid] = topic[b * 256 + tid];
  __syncthreads();
  float ah = bh[tid], am = bm[tid];
  for (int k = 0; k < 256; ++k) {
    float mk = xs[k];
    ah += mk * Wh[tid * 256 + k];
    am += mk * Wm[tid * 256 + k];
  }
  ws[OFF_HBUF + b * 256 + tid] = tanhf(ah);
  ws[OFF_M0   + b * 256 + tid] = tanhf(am);
  float a0 = bih[tid]       + bhh[tid];
  float a1 = bih[256 + tid] + bhh[256 + tid];
  float a2 = bih[512 + tid] + bhh[512 + tid];
  float a3 = bih[768 + tid] + bhh[768 + tid];
  for (int k = 0; k < 536; ++k) {
    float xk = xs[k];
    a0 += xk * Wih[(0 * 256 + tid) * 792 + k];
    a1 += xk * Wih[(1 * 256 + tid) * 792 + k];
    a2 += xk * Wih[(2 * 256 + tid) * 792 + k];
    a3 += xk * Wih[(3 * 256 + tid) * 792 + k];
  }
  float* gs = ws + OFF_GS + b * 1024;
  gs[tid] = a0; gs[256 + tid] = a1; gs[512 + tid] = a2; gs[768 + tid] = a3;
}

// ---------------- k_v: v = image @ Wv.T + bv ----------------
__global__ __launch_bounds__(256) void k_v(const float* __restrict__ image,
    const float* __restrict__ Wv, const float* __restrict__ bv, float* __restrict__ ws)
{
  __shared__ float As[PP * AP]; __shared__ float Bs[32 * BP];
  int nt = blockIdx.x, b = blockIdx.y, n0 = nt * 64;
  float* v = ws + OFF_V;
  gemm_tile<4>(As, Bs, 49, Wv, 256, 0, n0,
    [&](int r, int k) { return image[(b * PP + r) * EE + k]; },
    [&](int r, int c0, float4 o) {
      float4 bb = *(const float4*)&bv[n0 + c0];
      o.x += bb.x; o.y += bb.y; o.z += bb.z; o.w += bb.w;
      *(float4*)&v[(b * PP + r) * EE + n0 + c0] = o;
    });
}

// ---------------- k_gpre ----------------
__global__ __launch_bounds__(256) void k_gpre(const float* __restrict__ emb,
    const int* __restrict__ text, const float* __restrict__ Wih, float* __restrict__ ws)
{
  __shared__ float As[PP * AP]; __shared__ float Bs[32 * BP];
  int nt = blockIdx.x, b = blockIdx.y, n0 = nt * 64;
  const float* gs = ws + OFF_GS + b * 1024;
  float* gpre = ws + OFF_GPRE;
  gemm_tile<3>(As, Bs, 47, Wih, 792, 536, n0,
    [&](int r, int k) { return emb[(long long)text[b * TT + r] * EE + k]; },
    [&](int r, int c0, float4 o) {
      float* dst = gpre + (long long)r * 32768 + (n0 + c0) * 32 + b;
      dst[0]  = o.x + gs[n0 + c0];
      dst[32] = o.y + gs[n0 + c0 + 1];
      dst[64] = o.z + gs[n0 + c0 + 2];
      dst[96] = o.w + gs[n0 + c0 + 3];
    });
}

// ---------------- k_recur: LSTM recurrence, 32 groups (b) x 8 slices (q) ----------
// block (b,q) owns h-dims j in [32q, 32q+32), all 4 gates; Whh slice in VGPRs.
// thread: j_l = tid>>3, cc = tid&7 -> partial dots over k in [32cc, 32cc+32).
// sync: per-producer flags; ONLY WAVE 0 POLLS (R3 regression was 65K pollers
// flooding the LLC lines with agent-scope acquire loads). Relaxed poll +
// single acquire on success; s_sleep backoff.
__global__ __launch_bounds__(256, 1) void k_recur(const float* __restrict__ Whh,
    float* __restrict__ ws)
{
  int tid = threadIdx.x;
  int b = blockIdx.x & 31, q = blockIdx.x >> 5;
  int j_l = tid >> 3, cc = tid & 7;
  int qj = q * 32 + j_l;                          // global h-dim this octet owns

  // load Whh slice into registers: wreg[gate][c4] = 4 cols of row (gate*256+qj)
  float4 wreg[4][8];
#pragma unroll
  for (int gt = 0; gt < 4; ++gt) {
    const float* wr = Whh + (long long)((gt << 8) + qj) * 256 + (cc << 5);
#pragma unroll
    for (int c4 = 0; c4 < 8; ++c4) wreg[gt][c4] = *(const float4*)(wr + (c4 << 2));
  }

  float m = ws[OFF_M0 + b * 256 + qj];            // used only in lane cc==0
  float* hbuf = ws + OFF_HBUF;
  const float* gpre = ws + OFF_GPRE;
  float* h_all = ws + OFF_HALL;
  int* flags = (int*)(ws + OFF_FLAGS);            // flags[b*16+q]; b's 8 flags = 1 line

  for (int t = 0; t < ST; ++t) {
    // gate bias (gpre) for this j — independent of flags, issue early
    float g0 = 0.f, g1 = 0.f, g2 = 0.f, g3 = 0.f;
    if (cc == 0) {
      const float* gp = gpre + (long long)t * 32768;
      g0 = gp[((0 << 8) + qj) * 32 + b];
      g1 = gp[((1 << 8) + qj) * 32 + b];
      g2 = gp[((2 << 8) + qj) * 32 + b];
      g3 = gp[((3 << 8) + qj) * 32 + b];
    }
    if (t > 0) {
      if (tid < 64) {
        // lanes 0..7 watch the 8 producer flags of batch b
        for (;;) {
          int f = (tid < 8)
            ? __hip_atomic_load(&flags[b * 16 + tid], __ATOMIC_RELAXED,
                                __HIP_MEMORY_SCOPE_AGENT)
            : t;
          if (__ballot(f >= t) == ~0ull) break;
          __builtin_amdgcn_s_sleep(8);
        }
        if (tid < 8)  // acquire: syncs-with the release stores just observed
          (void)__hip_atomic_load(&flags[b * 16 + tid], __ATOMIC_ACQUIRE,
                                  __HIP_MEMORY_SCOPE_AGENT);
      }
      __syncthreads();
    }
    const float* hsrc = hbuf + (t & 1) * 8192 + b * 256 + (cc << 5);
    float4 h4[8];
#pragma unroll
    for (int c4 = 0; c4 < 8; ++c4) h4[c4] = *(const float4*)(hsrc + (c4 << 2));

    float ai = 0.f, af = 0.f, ag = 0.f, ao = 0.f;
#pragma unroll
    for (int c4 = 0; c4 < 8; ++c4) {
      float4 hv = h4[c4];
      ai += wreg[0][c4].x * hv.x + wreg[0][c4].y * hv.y + wreg[0][c4].z * hv.z + wreg[0][c4].w * hv.w;
      af += wreg[1][c4].x * hv.x + wreg[1][c4].y * hv.y + wreg[1][c4].z * hv.z + wreg[1][c4].w * hv.w;
      ag += wreg[2][c4].x * hv.x + wreg[2][c4].y * hv.y + wreg[2][c4].z * hv.z + wreg[2][c4].w * hv.w;
      ao += wreg[3][c4].x * hv.x + wreg[3][c4].y * hv.y + wreg[3][c4].z * hv.z + wreg[3][c4].w * hv.w;
    }
#pragma unroll
    for (int msk = 1; msk < 8; msk <<= 1) {
      ai += __shfl_xor(ai, msk, 64);
      af += __shfl_xor(af, msk, 64);
      ag += __shfl_xor(ag, msk, 64);
      ao += __shfl_xor(ao, msk, 64);
    }
    if (cc == 0) {
      ai += g0; af += g1; ag += g2; ao += g3;
      m = sigf(af) * m + sigf(ai) * tanhf(ag);
      float h = sigf(ao) * tanhf(m);
      hbuf[((t + 1) & 1) * 8192 + b * 256 + qj] = h;
      h_all[(long long)(b * ST + t) * 256 + qj] = h;
    }
    __syncthreads();                               // waves drain vmcnt before barrier
    if (t < ST - 1 && tid == 0) {
      __hip_atomic_store(&flags[b * 16 + q], t + 1, __ATOMIC_RELEASE,
                         __HIP_MEMORY_SCOPE_AGENT);
    }
  }
}

// ---------------- k_fc ----------------
__global__ __launch_bounds__(256) void k_fc(const float* __restrict__ Wfc,
    const float* __restrict__ bfc, float* __restrict__ ws)
{
  __shared__ float As[PP * AP]; __shared__ float Bs[32 * BP];
  int nt = blockIdx.x, b = blockIdx.y, n0 = nt * 64;
  const float* h_all = ws + OFF_HALL;
  float* FO = ws + OFF_FO;
  gemm_tile<3>(As, Bs, 47, Wfc, 256, 0, n0,
    [&](int r, int k) { return h_all[(long long)(b * ST + r) * 256 + k]; },
    [&](int r, int c0, float4 o) {
      float4 bb = *(const float4*)&bfc[n0 + c0];
      o.x = fmaxf(o.x + bb.x, 0.f); o.y = fmaxf(o.y + bb.y, 0.f);
      o.z = fmaxf(o.z + bb.z, 0.f); o.w = fmaxf(o.w + bb.w, 0.f);
      *(float4*)&FO[(long long)(b * ST + r) * 512 + n0 + c0] = o;
    });
}

// ---------------- k_hs ----------------
__global__ __launch_bounds__(256) void k_hs(const float* __restrict__ Whh2,
    const float* __restrict__ bhh2, const float* __restrict__ Wsw,
    const float* __restrict__ bsw, float* __restrict__ ws)
{
  __shared__ float As[PP * AP]; __shared__ float Bs[32 * BP];
  int nt = blockIdx.x, b = blockIdx.y;
  bool second = nt >= 4;
  int n0b = (nt & 3) * 64;
  const float* Bmat = second ? Wsw : Whh2;
  const float* bias = second ? bsw : bhh2;
  int aoff = second ? 256 : 0;
  int oout = second ? 256 : 0;
  const float* FO = ws + OFF_FO;
  float* HS = ws + OFF_HS;
  gemm_tile<3>(As, Bs, 47, Bmat, 256, 0, n0b,
    [&](int r, int k) { return FO[(long long)(b * ST + r) * 512 + aoff + k]; },
    [&](int r, int c0, float4 o) {
      float4 bb = *(const float4*)&bias[n0b + c0];
      o.x += bb.x; o.y += bb.y; o.z += bb.z; o.w += bb.w;
      *(float4*)&HS[(long long)(b * ST + r) * 512 + oout + n0b + c0] = o;
    });
}

// ---------------- k_att ----------------
__global__ __launch_bounds__(256) void k_att(const float* __restrict__ image,
    const float* __restrict__ Wz, const float* __restrict__ bz,
    const int* __restrict__ length, float* __restrict__ ws, float* __restrict__ out)
{
  int t = blockIdx.x, b = blockIdx.y, tid = threadIdx.x;
  int i = b * ST + t;
  float* att = out;
  bool valid = t < (length[b] - 1);
  if (!valid) {
    if (tid < 50) att[(long long)i * 50 + tid] = 0.f;
    return;
  }
  __shared__ float hhL[256], sL[256], hbL[256], sbL[256];
  __shared__ float zzL[52], aL[52];
  const float* FO = ws + OFF_FO;
  const float* HS = ws + OFF_HS;
  const float* v  = ws + OFF_V;
  float* CE = ws + OFF_CE;
  hhL[tid] = FO[(long long)i * 512 + tid];
  sL[tid]  = FO[(long long)i * 512 + 256 + tid];
  hbL[tid] = HS[(long long)i * 512 + tid];
  sbL[tid] = HS[(long long)i * 512 + 256 + tid];
  __syncthreads();
  int w = tid >> 6, l = tid & 63;
  for (int p = w; p < 50; p += 4) {
    int j0 = l * 4;
    float x0, x1, x2, x3;
    if (p < 49) {
      float4 vv = *(const float4*)&v[(long long)(b * PP + p) * EE + j0];
      x0 = vv.x; x1 = vv.y; x2 = vv.z; x3 = vv.w;
    } else {
      x0 = sbL[j0]; x1 = sbL[j0 + 1]; x2 = sbL[j0 + 2]; x3 = sbL[j0 + 3];
    }
    float4 wz4 = *(const float4*)&Wz[j0];
    float part = tanhf(x0 + hbL[j0]) * wz4.x + tanhf(x1 + hbL[j0 + 1]) * wz4.y
               + tanhf(x2 + hbL[j0 + 2]) * wz4.z + tanhf(x3 + hbL[j0 + 3]) * wz4.w;
    for (int o = 32; o; o >>= 1) part += __shfl_down(part, o, 64);
    if (l == 0) zzL[p] = part + bz[0];
  }
  __syncthreads();
  if (tid < 64) {
    float zv = (tid < 50) ? zzL[tid] : -3.4e38f;
    float mx = zv;
    for (int o = 32; o; o >>= 1) mx = fmaxf(mx, __shfl_xor(mx, o, 64));
    float e = (tid < 50) ? expf(zv - mx) : 0.f;
    float ssum = e;
    for (int o = 32; o; o >>= 1) ssum += __shfl_xor(ssum, o, 64);
    if (tid < 50) {
      float a = e / ssum;
      aL[tid] = a;
      att[(long long)i * 50 + tid] = a;
    }
  }
  __syncthreads();
  float cj = 0.f;
  for (int p = 0; p < 49; ++p) cj += aL[p] * image[(long long)(b * PP + p) * EE + tid];
  cj += aL[49] * sL[tid];
  CE[(long long)i * 256 + tid] = cj + hhL[tid];
}

// ---------------- k_cvtA: CE -> A-frag-layout bf16 hi/lo ----------------
__global__ __launch_bounds__(256) void k_cvtA(float* __restrict__ ws)
{
  int gid = blockIdx.x * 256 + threadIdx.x;   // 0..49151 (96*8*64)
  int lane = gid & 63;
  int kc = (gid >> 6) & 7;
  int mt16 = gid >> 9;
  int m = (mt16 << 4) + (lane & 15);
  int k0 = (kc << 5) + ((lane >> 4) << 3);
  float xs[8];
  if (m < 1504) {
    const float* src = ws + OFF_CE + (long long)m * 256 + k0;
    float4 a = *(const float4*)src;
    float4 c = *(const float4*)(src + 4);
    xs[0] = a.x; xs[1] = a.y; xs[2] = a.z; xs[3] = a.w;
    xs[4] = c.x; xs[5] = c.y; xs[6] = c.z; xs[7] = c.w;
  } else {
#pragma unroll
    for (int j = 0; j < 8; ++j) xs[j] = 0.f;
  }
  bf8v vh, vl;
#pragma unroll
  for (int j = 0; j < 8; ++j) {
    unsigned short h = f2bf(xs[j]);
    vh[j] = (short)h;
    vl[j] = (short)f2bf(xs[j] - __uint_as_float((unsigned)h << 16));
  }
  ((bf8v*)(ws + OFF_AHI))[gid] = vh;
  ((bf8v*)(ws + OFF_ALO))[gid] = vl;
}

// ---------------- k_cvtB: Wp -> B-frag-layout bf16 hi/lo ----------------
__global__ __launch_bounds__(256) void k_cvtB(const float* __restrict__ Wp,
                                              float* __restrict__ ws)
{
  int gid = blockIdx.x * 256 + threadIdx.x;   // 0..1023999 (2000*8*64)
  int lane = gid & 63;
  int kc = (gid >> 6) & 7;
  int nt16 = gid >> 9;
  int n = (nt16 << 4) + (lane & 15);
  int k0 = (kc << 5) + ((lane >> 4) << 3);
  const float* src = Wp + (long long)n * 256 + k0;
  float4 a = *(const float4*)src;
  float4 c = *(const float4*)(src + 4);
  float xs[8] = {a.x, a.y, a.z, a.w, c.x, c.y, c.z, c.w};
  bf8v vh, vl;
#pragma unroll
  for (int j = 0; j < 8; ++j) {
    unsigned short h = f2bf(xs[j]);
    vh[j] = (short)h;
    vl[j] = (short)f2bf(xs[j] - __uint_as_float((unsigned)h << 16));
  }
  ((bf8v*)(ws + OFF_BHI))[gid] = vh;
  ((bf8v*)(ws + OFF_BLO))[gid] = vl;
}

// ---------------- k_Dm: split-bf16 MFMA logits GEMM + softmax/argmax partials ----
__global__ __launch_bounds__(256) void k_Dm(const float* __restrict__ bp,
    const float* __restrict__ temp, float* __restrict__ ws, float* __restrict__ out)
{
  int tid = threadIdx.x;
  int wv = tid >> 6, lane = tid & 63, ln = lane & 15, quad = lane >> 4;
  int m0 = blockIdx.x * 64;
  int nw0 = blockIdx.y * 256 + wv * 64;
  const bf8v* Ah = (const bf8v*)(ws + OFF_AHI);
  const bf8v* Al = (const bf8v*)(ws + OFF_ALO);
  const bf8v* Bh = (const bf8v*)(ws + OFF_BHI);
  const bf8v* Bl = (const bf8v*)(ws + OFF_BLO);
  int mt0 = blockIdx.x * 4;
  int nt0 = nw0 >> 4;

  f4v acc[4][4];
#pragma unroll
  for (int mi = 0; mi < 4; ++mi)
#pragma unroll
    for (int ni = 0; ni < 4; ++ni) acc[mi][ni] = (f4v){0.f, 0.f, 0.f, 0.f};

  for (int kc = 0; kc < 8; ++kc) {
    bf8v ah[4], al[4];
#pragma unroll
    for (int mi = 0; mi < 4; ++mi) {
      int idx = (((mt0 + mi) << 3) + kc) * 64 + lane;
      ah[mi] = Ah[idx];
      al[mi] = Al[idx];
    }
#pragma unroll
    for (int ni = 0; ni < 4; ++ni) {
      int idx = (((nt0 + ni) << 3) + kc) * 64 + lane;
      bf8v bh = Bh[idx];
      bf8v bl = Bl[idx];
#pragma unroll
      for (int mi = 0; mi < 4; ++mi) {
        acc[mi][ni] = __builtin_amdgcn_mfma_f32_16x16x32_bf16(ah[mi], bh, acc[mi][ni], 0, 0, 0);
        acc[mi][ni] = __builtin_amdgcn_mfma_f32_16x16x32_bf16(al[mi], bh, acc[mi][ni], 0, 0, 0);
        acc[mi][ni] = __builtin_amdgcn_mfma_f32_16x16x32_bf16(ah[mi], bl, acc[mi][ni], 0, 0, 0);
      }
    }
  }

  float bpv[4];
#pragma unroll
  for (int ni = 0; ni < 4; ++ni) bpv[ni] = bp[nw0 + ni * 16 + ln];
  float* logp = out + OUT_LOGP;
  float* pmax = ws + OFF_PMAX;
  float* psum = ws + OFF_PSUM;
  int* pai = (int*)(ws + OFF_PAI);
  int ntidx = blockIdx.y * 4 + wv;

#pragma unroll
  for (int mi = 0; mi < 4; ++mi) {
    int row_base = m0 + mi * 16 + quad * 4;
#pragma unroll
    for (int r = 0; r < 4; ++r) {
      int row = row_base + r;
      if (row < 1504) {
        float x0 = acc[mi][0][r] + bpv[0];
        float x1 = acc[mi][1][r] + bpv[1];
        float x2 = acc[mi][2][r] + bpv[2];
        float x3 = acc[mi][3][r] + bpv[3];
        long long ro = (long long)row * VV + nw0 + ln;
        logp[ro]      = x0;
        logp[ro + 16] = x1;
        logp[ro + 32] = x2;
        logp[ro + 48] = x3;
        float mx = fmaxf(fmaxf(x0, x1), fmaxf(x2, x3));
#pragma unroll
        for (int msk = 1; msk < 16; msk <<= 1) mx = fmaxf(mx, __shfl_xor(mx, msk, 64));
        float it = 1.0f / temp[row / 47];
        float s = expf((x0 - mx) * it) + expf((x1 - mx) * it)
                + expf((x2 - mx) * it) + expf((x3 - mx) * it);
        float bv = x0; int bc = nw0 + ln;
        if (x1 > bv) { bv = x1; bc = nw0 + 16 + ln; }
        if (x2 > bv) { bv = x2; bc = nw0 + 32 + ln; }
        if (x3 > bv) { bv = x3; bc = nw0 + 48 + ln; }
#pragma unroll
        for (int msk = 1; msk < 16; msk <<= 1) {
          s += __shfl_xor(s, msk, 64);
          float ov = __shfl_xor(bv, msk, 64);
          int oc = __shfl_xor(bc, msk, 64);
          if (ov > bv || (ov == bv && oc < bc)) { bv = ov; bc = oc; }
        }
        if (ln == 0) {
          long long ii = (long long)row * 500 + ntidx;
          pmax[ii] = mx;
          psum[ii] = s;
          pai[ii] = bc;
        }
      }
    }
  }
}

// ---------------- k_E0: reduce per-tile partials -> row stats + txt ----------------
__global__ __launch_bounds__(256) void k_E0(const int* __restrict__ length,
    const float* __restrict__ temp, float* __restrict__ ws, float* __restrict__ out)
{
  int i = blockIdx.x, tid = threadIdx.x;
  int b = i / ST, t = i % ST;
  float* txt = out + OUT_TXT;
  if (t >= length[b] - 1) { if (tid == 0) txt[i] = 0.f; return; }
  const float* pmax = ws + OFF_PMAX + (long long)i * 500;
  const float* psum = ws + OFF_PSUM + (long long)i * 500;
  const int* pai = (int*)(ws + OFF_PAI) + (long long)i * 500;
  __shared__ float sred[4]; __shared__ float s2[4]; __shared__ float s3[4]; __shared__ int s4[4];
  int w = tid >> 6;
  float mx = -3.4e38f;
  for (int nt = tid; nt < 500; nt += 256) mx = fmaxf(mx, pmax[nt]);
  for (int o = 32; o; o >>= 1) mx = fmaxf(mx, __shfl_xor(mx, o, 64));
  if ((tid & 63) == 0) sred[w] = mx;
  __syncthreads();
  float M = fmaxf(fmaxf(sred[0], sred[1]), fmaxf(sred[2], sred[3]));
  float it = 1.0f / temp[b];
  float S = 0.f; float bv = -3.4e38f; int bi = 0;
  for (int nt = tid; nt < 500; nt += 256) {
    float pm = pmax[nt];
    S += psum[nt] * expf((pm - M) * it);
    int ii = pai[nt];
    if (pm > bv || (pm == bv && ii < bi)) { bv = pm; bi = ii; }
  }
  for (int o = 32; o; o >>= 1) {
    S += __shfl_xor(S, o, 64);
    float vv = __shfl_xor(bv, o, 64);
    int ii = __shfl_xor(bi, o, 64);
    if (vv > bv || (vv == bv && ii < bi)) { bv = vv; bi = ii; }
  }
  if ((tid & 63) == 0) { s2[w] = S; s3[w] = bv; s4[w] = bi; }
  __syncthreads();
  if (tid == 0) {
    float St = s2[0] + s2[1] + s2[2] + s2[3];
    float bvv = s3[0]; int bii = s4[0];
    for (int u = 1; u < 4; ++u)
      if (s3[u] > bvv || (s3[u] == bvv && s4[u] < bii)) { bvv = s3[u]; bii = s4[u]; }
    ws[OFF_ROWM + i] = M;
    ws[OFF_ROWLS + i] = logf(St);
    txt[i] = (float)bii;
  }
}

// ---------------- k_E: in-place logits -> logp ----------------
__global__ __launch_bounds__(256) void k_E(const int* __restrict__ length,
    const float* __restrict__ temp, const float* __restrict__ ws, float* __restrict__ out)
{
  int i = blockIdx.y;
  int f4 = blockIdx.x * 256 + threadIdx.x;
  if (f4 >= 8000) return;
  int b = i / ST, t = i % ST;
  float4* p = (float4*)(out + OUT_LOGP + (long long)i * VV) + f4;
  if (t >= length[b] - 1) { *p = make_float4(0.f, 0.f, 0.f, 0.f); return; }
  float M = ws[OFF_ROWM + i], LS = ws[OFF_ROWLS + i];
  float it = 1.0f / temp[b];
  float4 x = *p;
  x.x = (x.x - M) * it - LS;
  x.y = (x.y - M) * it - LS;
  x.z = (x.z - M) * it - LS;
  x.w = (x.w - M) * it - LS;
  *p = x;
}

// ---------------- launch ----------------
extern "C" void kernel_launch(void* const* d_in, const int* in_sizes, int n_in,
                              void* d_out, int out_size, void* d_ws, size_t ws_size,
                              hipStream_t stream) {
  const float* image = (const float*)d_in[0];
  const float* vp    = (const float*)d_in[1];
  const float* label = (const float*)d_in[2];
  const float* topic = (const float*)d_in[3];
  const float* temp  = (const float*)d_in[4];
  const int*   text  = (const int*)d_in[5];
  const int*   length= (const int*)d_in[6];
  const float* emb   = (const float*)d_in[7];
  const float* Wv  = (const float*)d_in[8];  const float* bv  = (const float*)d_in[9];
  const float* Wh  = (const float*)d_in[10]; const float* bh  = (const float*)d_in[11];
  const float* Wm  = (const float*)d_in[12]; const float* bm  = (const float*)d_in[13];
  const float* Wih = (const float*)d_in[14]; const float* bih = (const float*)d_in[15];
  const float* Whh = (const float*)d_in[16]; const float* bhh = (const float*)d_in[17];
  const float* Wfc = (const float*)d_in[18]; const float* bfc = (const float*)d_in[19];
  const float* Whh2= (const float*)d_in[20]; const float* bhh2= (const float*)d_in[21];
  const float* Wsw = (const float*)d_in[22]; const float* bsw = (const float*)d_in[23];
  const float* Wz  = (const float*)d_in[24]; const float* bz  = (const float*)d_in[25];
  const float* Wp  = (const float*)d_in[26]; const float* bp  = (const float*)d_in[27];
  float* ws = (float*)d_ws;
  float* out = (float*)d_out;

  hipMemsetAsync(ws + OFF_FLAGS, 0, 512 * sizeof(int), stream);   // flags (poisoned 0xAA otherwise)
  k_prep<<<32, 256, 0, stream>>>(image, vp, label, topic, Wh, bh, Wm, bm, Wih, bih, bhh, ws);
  k_v<<<dim3(4, 32), 256, 0, stream>>>(image, Wv, bv, ws);
  k_gpre<<<dim3(16, 32), 256, 0, stream>>>(emb, text, Wih, ws);
  k_recur<<<256, 256, 0, stream>>>(Whh, ws);
  k_fc<<<dim3(8, 32), 256, 0, stream>>>(Wfc, bfc, ws);
  k_hs<<<dim3(8, 32), 256, 0, stream>>>(Whh2, bhh2, Wsw, bsw, ws);
  k_att<<<dim3(47, 32), 256, 0, stream>>>(image, Wz, bz, length, ws, out);
  k_cvtA<<<192, 256, 0, stream>>>(ws);
  k_cvtB<<<4000, 256, 0, stream>>>(Wp, ws);
  k_Dm<<<dim3(24, 125), 256, 0, stream>>>(bp, temp, ws, out);
  k_E0<<<1504, 256, 0, stream>>>(length, temp, ws, out);
  k_E<<<dim3(32, 1504), 256, 0, stream>>>(length, temp, ws, out);
}